// Round 2
// baseline (803.467 us; speedup 1.0000x reference)
//
#include <hip/hip_runtime.h>

#define N_NODES 200000
#define N_EDGES 3200000
#define FEATS   256
#define NC      32

__device__ __forceinline__ float atomAddF(float* p, float v) {
    return unsafeAtomicAdd(p, v);
}

// ---------------------------------------------------------------------------
// Kernel 1: h = x @ W^T + bias   [N,32]
// x read directly from global (zero reuse -> no LDS staging).
// W in LDS as k-pairs: wl[(k>>1)*64 + c*2 + (k&1)]  -> ds_read_b64, 2-way
// bank aliasing only (free). 8 rows/thread, 64 rows/block-tile.
// Fused: S1[c] += (u[n]/N)*h[n,c],  S2 += (...)^2
// ---------------------------------------------------------------------------
__global__ __launch_bounds__(256) void k_linear(
    const float* __restrict__ x, const float* __restrict__ Wmat,
    const float* __restrict__ bias, const float* __restrict__ u_sum,
    float* __restrict__ h, float* __restrict__ S1, float* __restrict__ S2)
{
    __shared__ float wl[128 * 64];     // 32 KB
    __shared__ float red[256];

    for (int i = threadIdx.x; i < NC * FEATS; i += 256) {
        int c = i >> 8, k = i & 255;
        wl[(k >> 1) * 64 + (c << 1) + (k & 1)] = Wmat[i];
    }
    __syncthreads();

    const int c = threadIdx.x & 31;
    const int g = threadIdx.x >> 5;           // 0..7, 8 rows each
    const float b = bias[c];
    const float invn = 1.0f / (float)N_NODES;
    float s1 = 0.f, s2 = 0.f;

    for (int base = blockIdx.x * 64; base < N_NODES; base += gridDim.x * 64) {
        const float* xp = x + (size_t)(base + g * 8) * FEATS;
        float acc[8];
        #pragma unroll
        for (int r = 0; r < 8; ++r) acc[r] = b;

        #pragma unroll 4
        for (int k = 0; k < FEATS; k += 4) {
            float2 wp0 = *(const float2*)&wl[(k >> 1) * 64 + (c << 1)];
            float2 wp1 = *(const float2*)&wl[((k >> 1) + 1) * 64 + (c << 1)];
            #pragma unroll
            for (int r = 0; r < 8; ++r) {
                float4 xv = *(const float4*)(xp + (size_t)r * FEATS + k);
                acc[r] = fmaf(xv.x, wp0.x, acc[r]);
                acc[r] = fmaf(xv.y, wp0.y, acc[r]);
                acc[r] = fmaf(xv.z, wp1.x, acc[r]);
                acc[r] = fmaf(xv.w, wp1.y, acc[r]);
            }
        }

        #pragma unroll
        for (int r = 0; r < 8; ++r) {
            const int row = base + g * 8 + r;
            h[(size_t)row * NC + c] = acc[r];
            float a = u_sum[row] * invn * acc[r];
            s1 += a;
            s2 += a * a;
        }
    }

    // block reduce S1 (per class) and S2 (scalar)
    red[threadIdx.x] = s1;
    __syncthreads();
    if (threadIdx.x < 32) {
        float t = 0.f;
        #pragma unroll
        for (int j = 0; j < 8; ++j) t += red[threadIdx.x + 32 * j];
        atomAddF(&S1[threadIdx.x], t);
    }
    __syncthreads();
    red[threadIdx.x] = s2;
    __syncthreads();
    for (int off = 128; off > 0; off >>= 1) {
        if (threadIdx.x < off) red[threadIdx.x] += red[threadIdx.x + off];
        __syncthreads();
    }
    if (threadIdx.x == 0) atomAddF(S2, red[0]);
}

// ---------------------------------------------------------------------------
// Counting sort by dst: hist -> scan -> scatter into sorted order
// ---------------------------------------------------------------------------
__global__ __launch_bounds__(256) void k_hist(
    const int* __restrict__ dst, int* __restrict__ cnt)
{
    int e = blockIdx.x * 256 + threadIdx.x;      // grid sized exactly
    atomicAdd(&cnt[dst[e]], 1);
}

__global__ __launch_bounds__(256) void k_scan_a(
    const int* __restrict__ cnt, int* __restrict__ partial,
    int* __restrict__ bsum, int n)
{
    __shared__ int sm[256];
    int i = blockIdx.x * 256 + threadIdx.x;
    int v = (i < n) ? cnt[i] : 0;
    sm[threadIdx.x] = v;
    __syncthreads();
    for (int off = 1; off < 256; off <<= 1) {
        int t = (threadIdx.x >= off) ? sm[threadIdx.x - off] : 0;
        __syncthreads();
        sm[threadIdx.x] += t;
        __syncthreads();
    }
    if (i < n) partial[i] = sm[threadIdx.x] - v;   // block-local exclusive
    if (threadIdx.x == 255) bsum[blockIdx.x] = sm[255];
}

__global__ __launch_bounds__(256) void k_scan_b(int* __restrict__ bsum, int nb)
{
    __shared__ int sm[256];
    int carry = 0;
    for (int base = 0; base < nb; base += 256) {
        int i = base + (int)threadIdx.x;
        int v = (i < nb) ? bsum[i] : 0;
        sm[threadIdx.x] = v;
        __syncthreads();
        for (int off = 1; off < 256; off <<= 1) {
            int t = (threadIdx.x >= off) ? sm[threadIdx.x - off] : 0;
            __syncthreads();
            sm[threadIdx.x] += t;
            __syncthreads();
        }
        int incl = sm[threadIdx.x];
        int total = sm[255];
        if (i < nb) bsum[i] = carry + incl - v;    // exclusive across all
        carry += total;
        __syncthreads();
    }
}

__global__ __launch_bounds__(256) void k_scan_c(
    const int* __restrict__ partial, const int* __restrict__ bsum,
    int* __restrict__ offs, int* __restrict__ pos, int n)
{
    int i = blockIdx.x * 256 + threadIdx.x;
    if (i < n) {
        int v = partial[i] + bsum[blockIdx.x];
        offs[i] = v;
        pos[i]  = v;
    }
}

__global__ __launch_bounds__(256) void k_sortscatter(
    const int* __restrict__ src, const float* __restrict__ w,
    const int* __restrict__ dst, int* __restrict__ pos,
    int2* __restrict__ sorted)
{
    int e = blockIdx.x * 256 + threadIdx.x;      // grid sized exactly
    int d = dst[e];
    int p = atomicAdd(&pos[d], 1);
    int2 v;
    v.x = src[e];
    v.y = __float_as_int(w[e]);
    sorted[p] = v;
}

// ---------------------------------------------------------------------------
// Gather: 32 lanes per node, y written once, colsum fused.
// ---------------------------------------------------------------------------
__global__ __launch_bounds__(256) void k_gather(
    const int2* __restrict__ sorted, const int* __restrict__ offs,
    const int* __restrict__ cnt, const float* __restrict__ h,
    float* __restrict__ y, float* __restrict__ colsum)
{
    __shared__ float red[256];
    const int c = threadIdx.x & 31;
    float scol = 0.f;

    const int ntiles = N_NODES / 8;              // 8 nodes per block-iter
    for (int nb = blockIdx.x; nb < ntiles; nb += gridDim.x) {
        const int n = nb * 8 + (threadIdx.x >> 5);
        const int beg = offs[n];
        const int deg = cnt[n];
        float s = 0.f;
        for (int j = 0; j < deg; ++j) {
            int2 p = sorted[beg + j];
            s = fmaf(h[(size_t)p.x * NC + c], __int_as_float(p.y), s);
        }
        y[(size_t)n * NC + c] = s;
        scol += s;
    }

    red[threadIdx.x] = scol;
    __syncthreads();
    if (threadIdx.x < 32) {
        float t = 0.f;
        #pragma unroll
        for (int j = 0; j < 8; ++j) t += red[threadIdx.x + 32 * j];
        atomAddF(&colsum[threadIdx.x], t);
    }
}

// ---------------------------------------------------------------------------
// Fallback path (small workspace): atomic scatter + colsum
// ---------------------------------------------------------------------------
__global__ __launch_bounds__(256) void k_scatter_atomic(
    const float* __restrict__ h, const float* __restrict__ w,
    const int* __restrict__ src, const int* __restrict__ dst,
    float* __restrict__ y)
{
    const long long total  = (long long)N_EDGES * NC;
    const long long stride = (long long)gridDim.x * 256;
    for (long long i = (long long)blockIdx.x * 256 + threadIdx.x;
         i < total; i += stride) {
        const int e = (int)(i >> 5);
        const int c = (int)(i & 31);
        atomAddF(&y[(size_t)dst[e] * NC + c], h[(size_t)src[e] * NC + c] * w[e]);
    }
}

__global__ __launch_bounds__(256) void k_colsum(
    const float* __restrict__ y, float* __restrict__ colsum)
{
    __shared__ float red[256];
    const long long total  = (long long)N_NODES * NC;
    const long long stride = (long long)gridDim.x * 256;
    float s = 0.f;
    for (long long i = (long long)blockIdx.x * 256 + threadIdx.x;
         i < total; i += stride)
        s += y[i];
    red[threadIdx.x] = s;
    __syncthreads();
    if (threadIdx.x < 32) {
        float t = 0.f;
        #pragma unroll
        for (int j = 0; j < 8; ++j) t += red[threadIdx.x + 32 * j];
        atomAddF(&colsum[threadIdx.x], t);
    }
}

// ---------------------------------------------------------------------------
// loss = (S2 - 2*sum_c m_c*S1_c + N*sum_c m_c^2) / (N*C)
// acc: [0..31] colsum_y, [32..63] S1, [64] S2
// ---------------------------------------------------------------------------
__global__ void k_final(const float* __restrict__ acc, float* __restrict__ loss_out)
{
    double cross = 0.0, msq = 0.0;
    for (int c = 0; c < NC; ++c) {
        double m = (double)acc[c] / (double)N_NODES;
        cross += m * (double)acc[32 + c];
        msq   += m * m;
    }
    double loss = ((double)acc[64] - 2.0 * cross + (double)N_NODES * msq)
                  / ((double)N_NODES * (double)NC);
    *loss_out = (float)loss;
}

extern "C" void kernel_launch(void* const* d_in, const int* in_sizes, int n_in,
                              void* d_out, int out_size, void* d_ws, size_t ws_size,
                              hipStream_t stream)
{
    const float* x   = (const float*)d_in[0];
    const float* w   = (const float*)d_in[1];
    const float* u   = (const float*)d_in[2];
    const float* Wm  = (const float*)d_in[3];
    const float* Wb  = (const float*)d_in[4];
    const int*   src = (const int*)d_in[5];
    const int*   dst = (const int*)d_in[6];

    float* out = (float*)d_out;                  // y [N*32] then loss [1]

    // workspace layout
    uint8_t* w8 = (uint8_t*)d_ws;
    float* acc  = (float*)w8;                    // 256 floats (colsum/S1/S2)
    int*   cnt  = (int*)(w8 + 1024);
    int*   offs = cnt + N_NODES;
    int*   pos  = offs + N_NODES;
    int*   bsum = pos + N_NODES;                 // 1024 ints
    float* h    = (float*)(bsum + 1024);         // 25.6 MB
    int2*  sorted = (int2*)(h + (size_t)N_NODES * NC);  // 25.6 MB

    const size_t need = 1024 + (size_t)(3 * N_NODES + 1024) * 4
                      + (size_t)N_NODES * NC * 4 + (size_t)N_EDGES * 8;

    hipMemsetAsync(acc, 0, 256 * sizeof(float), stream);

    if (ws_size >= need) {
        hipMemsetAsync(cnt, 0, (size_t)N_NODES * sizeof(int), stream);

        k_linear<<<1024, 256, 0, stream>>>(x, Wm, Wb, u, h, acc + 32, acc + 64);

        const int NB = (N_NODES + 255) / 256;    // 782
        k_hist       <<<N_EDGES / 256, 256, 0, stream>>>(dst, cnt);
        k_scan_a     <<<NB, 256, 0, stream>>>(cnt, offs /*partial*/, bsum, N_NODES);
        k_scan_b     <<<1, 256, 0, stream>>>(bsum, NB);
        k_scan_c     <<<NB, 256, 0, stream>>>(offs /*partial*/, bsum, pos, pos, N_NODES);
        // NOTE: offs currently holds partials; scan_c must write both offs and pos.
        // Re-run pattern: write offs properly:
        k_scan_c     <<<NB, 256, 0, stream>>>(offs /*partial*/, bsum, offs, pos, N_NODES);
        k_sortscatter<<<N_EDGES / 256, 256, 0, stream>>>(src, w, dst, pos, sorted);
        k_gather     <<<2048, 256, 0, stream>>>(sorted, offs, cnt, h, out, acc);
    } else {
        // fallback: atomic scatter path (needs only h + acc)
        float* h2 = (float*)w8 + 256;
        hipMemsetAsync(d_out, 0, (size_t)out_size * sizeof(float), stream);
        k_linear        <<<1024, 256, 0, stream>>>(x, Wm, Wb, u, h2, acc + 32, acc + 64);
        k_scatter_atomic<<<8192, 256, 0, stream>>>(h2, w, src, dst, out);
        k_colsum        <<<2048, 256, 0, stream>>>(out, acc);
    }

    k_final<<<1, 1, 0, stream>>>(acc, out + (size_t)N_NODES * NC);
}

// Round 3
// 505.333 us; speedup vs baseline: 1.5900x; 1.5900x over previous
//
#include <hip/hip_runtime.h>
#include <hip/hip_bf16.h>

#define N_NODES 200000
#define N_EDGES 3200000
#define FEATS   256
#define NC      32

typedef __attribute__((ext_vector_type(8))) short bf16x8;
typedef __attribute__((ext_vector_type(4))) float f32x4;

__device__ __forceinline__ float atomAddF(float* p, float v) {
    return unsafeAtomicAdd(p, v);
}
__device__ __forceinline__ short f2bf(float f) {
    return (short)__bfloat16_as_ushort(__float2bfloat16(f));
}

// ---------------------------------------------------------------------------
// Kernel 1: h = x @ W^T + bias  via bf16 MFMA (threshold has ~9x headroom).
// Per wave: 16-row tile. B (W^T) pre-converted to 16 reg fragments once per
// block. x streamed from global (f32x4 x2 per lane per K-step), converted
// in-register. No LDS in the main loop.
// Fragment convention (m97-style, verified-by-proxy): A from x[M][K] rows,
// B from W[C][K] rows, identical lane pattern: lane l -> row/col = l&15,
// k = (l>>4)*8 + j. C/D (m89-verified): col = l&15, row = (l>>4)*4 + reg.
// Fused: S1[c] += (u[n]/N)*h[n,c],  S2 += (...)^2
// ---------------------------------------------------------------------------
__global__ __launch_bounds__(256, 3) void k_linear(
    const float* __restrict__ x, const float* __restrict__ Wmat,
    const float* __restrict__ bias, const float* __restrict__ u_sum,
    float* __restrict__ h, float* __restrict__ S1, float* __restrict__ S2)
{
    __shared__ float lds_s1[4][32];
    __shared__ float lds_s2[4];

    const int lane = threadIdx.x & 63;
    const int wv   = threadIdx.x >> 6;      // 0..3
    const int lr   = lane & 15;
    const int kc   = lane >> 4;             // 0..3

    // B fragments: bfr[kt][ct]; k = kt*32 + kc*8 + j, c = ct*16 + lr
    bf16x8 bfr[8][2];
    #pragma unroll
    for (int ct = 0; ct < 2; ++ct) {
        const float* wp = Wmat + (size_t)(ct * 16 + lr) * FEATS + kc * 8;
        #pragma unroll
        for (int kt = 0; kt < 8; ++kt) {
            f32x4 v0 = *(const f32x4*)(wp + kt * 32);
            f32x4 v1 = *(const f32x4*)(wp + kt * 32 + 4);
            bf16x8 b;
            b[0]=f2bf(v0.x); b[1]=f2bf(v0.y); b[2]=f2bf(v0.z); b[3]=f2bf(v0.w);
            b[4]=f2bf(v1.x); b[5]=f2bf(v1.y); b[6]=f2bf(v1.z); b[7]=f2bf(v1.w);
            bfr[kt][ct] = b;
        }
    }

    const float bias0 = bias[lr], bias1 = bias[16 + lr];
    const float invn = 1.0f / (float)N_NODES;
    float s1_0 = 0.f, s1_1 = 0.f, s2 = 0.f;

    const int ntiles = N_NODES / 16;        // 12500 wave-tiles
    for (int t = blockIdx.x * 4 + wv; t < ntiles; t += gridDim.x * 4) {
        const int base = t * 16;
        const float* xp = x + (size_t)(base + lr) * FEATS + kc * 8;
        f32x4 acc0 = {bias0, bias0, bias0, bias0};
        f32x4 acc1 = {bias1, bias1, bias1, bias1};
        #pragma unroll
        for (int kt = 0; kt < 8; ++kt) {
            f32x4 v0 = *(const f32x4*)(xp + kt * 32);
            f32x4 v1 = *(const f32x4*)(xp + kt * 32 + 4);
            bf16x8 a;
            a[0]=f2bf(v0.x); a[1]=f2bf(v0.y); a[2]=f2bf(v0.z); a[3]=f2bf(v0.w);
            a[4]=f2bf(v1.x); a[5]=f2bf(v1.y); a[6]=f2bf(v1.z); a[7]=f2bf(v1.w);
            acc0 = __builtin_amdgcn_mfma_f32_16x16x32_bf16(a, bfr[kt][0], acc0, 0, 0, 0);
            acc1 = __builtin_amdgcn_mfma_f32_16x16x32_bf16(a, bfr[kt][1], acc1, 0, 0, 0);
        }
        #pragma unroll
        for (int i = 0; i < 4; ++i) {
            const int row = base + kc * 4 + i;
            h[(size_t)row * NC + lr]      = acc0[i];
            h[(size_t)row * NC + 16 + lr] = acc1[i];
            const float um = u_sum[row] * invn;
            float a0 = um * acc0[i], a1 = um * acc1[i];
            s1_0 += a0; s1_1 += a1;
            s2 += a0 * a0 + a1 * a1;
        }
    }

    // reduce s1 across the 4 kc-groups (same lr) via xor 16/32
    s1_0 += __shfl_xor(s1_0, 16); s1_0 += __shfl_xor(s1_0, 32);
    s1_1 += __shfl_xor(s1_1, 16); s1_1 += __shfl_xor(s1_1, 32);
    #pragma unroll
    for (int off = 1; off < 64; off <<= 1) s2 += __shfl_xor(s2, off);
    if (lane < 16) { lds_s1[wv][lr] = s1_0; lds_s1[wv][16 + lr] = s1_1; }
    if (lane == 0) lds_s2[wv] = s2;
    __syncthreads();
    if (threadIdx.x < 32) {
        float t4 = lds_s1[0][threadIdx.x] + lds_s1[1][threadIdx.x]
                 + lds_s1[2][threadIdx.x] + lds_s1[3][threadIdx.x];
        atomAddF(&S1[threadIdx.x], t4);
    }
    if (threadIdx.x == 32)
        atomAddF(S2, lds_s2[0] + lds_s2[1] + lds_s2[2] + lds_s2[3]);
}

// ---------------------------------------------------------------------------
// Counting sort by dst
// ---------------------------------------------------------------------------
__global__ __launch_bounds__(256) void k_hist(
    const int* __restrict__ dst, int* __restrict__ cnt)
{
    int e = blockIdx.x * 256 + threadIdx.x;
    atomicAdd(&cnt[dst[e]], 1);
}

__global__ __launch_bounds__(256) void k_scan_a(
    const int* __restrict__ cnt, int* __restrict__ partial,
    int* __restrict__ bsum, int n)
{
    __shared__ int sm[256];
    int i = blockIdx.x * 256 + threadIdx.x;
    int v = (i < n) ? cnt[i] : 0;
    sm[threadIdx.x] = v;
    __syncthreads();
    for (int off = 1; off < 256; off <<= 1) {
        int t = (threadIdx.x >= off) ? sm[threadIdx.x - off] : 0;
        __syncthreads();
        sm[threadIdx.x] += t;
        __syncthreads();
    }
    if (i < n) partial[i] = sm[threadIdx.x] - v;
    if (threadIdx.x == 255) bsum[blockIdx.x] = sm[255];
}

__global__ __launch_bounds__(256) void k_scan_b(int* __restrict__ bsum, int nb)
{
    __shared__ int sm[256];
    int carry = 0;
    for (int base = 0; base < nb; base += 256) {
        int i = base + (int)threadIdx.x;
        int v = (i < nb) ? bsum[i] : 0;
        sm[threadIdx.x] = v;
        __syncthreads();
        for (int off = 1; off < 256; off <<= 1) {
            int t = (threadIdx.x >= off) ? sm[threadIdx.x - off] : 0;
            __syncthreads();
            sm[threadIdx.x] += t;
            __syncthreads();
        }
        int incl = sm[threadIdx.x];
        int total = sm[255];
        if (i < nb) bsum[i] = carry + incl - v;
        carry += total;
        __syncthreads();
    }
}

// partial lives in `pos`; writes offs[i] = pos[i] = global exclusive prefix
__global__ __launch_bounds__(256) void k_scan_c(
    const int* __restrict__ bsum, int* __restrict__ offs,
    int* __restrict__ pos, int n)
{
    int i = blockIdx.x * 256 + threadIdx.x;
    if (i < n) {
        int v = pos[i] + bsum[blockIdx.x];
        offs[i] = v;
        pos[i]  = v;
    }
}

__global__ __launch_bounds__(256) void k_sortscatter(
    const int* __restrict__ src, const float* __restrict__ w,
    const int* __restrict__ dst, int* __restrict__ pos,
    int2* __restrict__ sorted)
{
    int e = blockIdx.x * 256 + threadIdx.x;
    int d = dst[e];
    int p = atomicAdd(&pos[d], 1);
    int2 v;
    v.x = src[e];
    v.y = __float_as_int(w[e]);
    sorted[p] = v;
}

// ---------------------------------------------------------------------------
// Gather: 32 lanes per node, y written once, colsum fused. Prefetched edges.
// ---------------------------------------------------------------------------
__global__ __launch_bounds__(256) void k_gather(
    const int2* __restrict__ sorted, const int* __restrict__ offs,
    const int* __restrict__ cnt, const float* __restrict__ h,
    float* __restrict__ y, float* __restrict__ colsum)
{
    __shared__ float red[256];
    const int c = threadIdx.x & 31;
    const int grp = threadIdx.x >> 5;       // 0..7
    float scol = 0.f;

    const int ngroups = N_NODES / 8;        // 25000
    for (int tb = blockIdx.x; tb < ngroups; tb += gridDim.x) {
        const int n = tb * 8 + grp;
        const int beg = offs[n];
        const int deg = cnt[n];
        float s = 0.f;
        int2 p = (deg > 0) ? sorted[beg] : make_int2(0, 0);
        for (int j = 1; j < deg; ++j) {
            int2 pn = sorted[beg + j];      // prefetch next edge
            s = fmaf(h[(size_t)p.x * NC + c], __int_as_float(p.y), s);
            p = pn;
        }
        if (deg > 0)
            s = fmaf(h[(size_t)p.x * NC + c], __int_as_float(p.y), s);
        y[(size_t)n * NC + c] = s;
        scol += s;
    }

    red[threadIdx.x] = scol;
    __syncthreads();
    if (threadIdx.x < 32) {
        float t = 0.f;
        #pragma unroll
        for (int j = 0; j < 8; ++j) t += red[threadIdx.x + 32 * j];
        atomAddF(&colsum[threadIdx.x], t);
    }
}

// ---------------------------------------------------------------------------
// Fallback path (small workspace)
// ---------------------------------------------------------------------------
__global__ __launch_bounds__(256) void k_scatter_atomic(
    const float* __restrict__ h, const float* __restrict__ w,
    const int* __restrict__ src, const int* __restrict__ dst,
    float* __restrict__ y)
{
    const long long total  = (long long)N_EDGES * NC;
    const long long stride = (long long)gridDim.x * 256;
    for (long long i = (long long)blockIdx.x * 256 + threadIdx.x;
         i < total; i += stride) {
        const int e = (int)(i >> 5);
        const int c = (int)(i & 31);
        atomAddF(&y[(size_t)dst[e] * NC + c], h[(size_t)src[e] * NC + c] * w[e]);
    }
}

__global__ __launch_bounds__(256) void k_colsum(
    const float* __restrict__ y, float* __restrict__ colsum)
{
    __shared__ float red[256];
    const long long total  = (long long)N_NODES * NC;
    const long long stride = (long long)gridDim.x * 256;
    float s = 0.f;
    for (long long i = (long long)blockIdx.x * 256 + threadIdx.x;
         i < total; i += stride)
        s += y[i];
    red[threadIdx.x] = s;
    __syncthreads();
    if (threadIdx.x < 32) {
        float t = 0.f;
        #pragma unroll
        for (int j = 0; j < 8; ++j) t += red[threadIdx.x + 32 * j];
        atomAddF(&colsum[threadIdx.x], t);
    }
}

// ---------------------------------------------------------------------------
// loss; acc: [0..31] colsum_y, [32..63] S1, [64] S2
// ---------------------------------------------------------------------------
__global__ void k_final(const float* __restrict__ acc, float* __restrict__ loss_out)
{
    double cross = 0.0, msq = 0.0;
    for (int c = 0; c < NC; ++c) {
        double m = (double)acc[c] / (double)N_NODES;
        cross += m * (double)acc[32 + c];
        msq   += m * m;
    }
    double loss = ((double)acc[64] - 2.0 * cross + (double)N_NODES * msq)
                  / ((double)N_NODES * (double)NC);
    *loss_out = (float)loss;
}

extern "C" void kernel_launch(void* const* d_in, const int* in_sizes, int n_in,
                              void* d_out, int out_size, void* d_ws, size_t ws_size,
                              hipStream_t stream)
{
    const float* x   = (const float*)d_in[0];
    const float* w   = (const float*)d_in[1];
    const float* u   = (const float*)d_in[2];
    const float* Wm  = (const float*)d_in[3];
    const float* Wb  = (const float*)d_in[4];
    const int*   src = (const int*)d_in[5];
    const int*   dst = (const int*)d_in[6];

    float* out = (float*)d_out;                  // y [N*32] then loss [1]

    uint8_t* w8 = (uint8_t*)d_ws;
    float* acc  = (float*)w8;                    // 256 floats
    int*   cnt  = (int*)(w8 + 1024);
    int*   offs = cnt + N_NODES;
    int*   pos  = offs + N_NODES;
    int*   bsum = pos + N_NODES;                 // 1024 ints
    float* h    = (float*)(bsum + 1024);         // 25.6 MB
    int2*  sorted = (int2*)(h + (size_t)N_NODES * NC);  // 25.6 MB

    const size_t need = 1024 + (size_t)(3 * N_NODES + 1024) * 4
                      + (size_t)N_NODES * NC * 4 + (size_t)N_EDGES * 8;

    hipMemsetAsync(acc, 0, 256 * sizeof(float), stream);

    if (ws_size >= need) {
        hipMemsetAsync(cnt, 0, (size_t)N_NODES * sizeof(int), stream);

        k_linear<<<1024, 256, 0, stream>>>(x, Wm, Wb, u, h, acc + 32, acc + 64);

        const int NB = (N_NODES + 255) / 256;    // 782
        k_hist       <<<N_EDGES / 256, 256, 0, stream>>>(dst, cnt);
        k_scan_a     <<<NB, 256, 0, stream>>>(cnt, pos /*partial*/, bsum, N_NODES);
        k_scan_b     <<<1, 256, 0, stream>>>(bsum, NB);
        k_scan_c     <<<NB, 256, 0, stream>>>(bsum, offs, pos, N_NODES);
        k_sortscatter<<<N_EDGES / 256, 256, 0, stream>>>(src, w, dst, pos, sorted);
        k_gather     <<<2048, 256, 0, stream>>>(sorted, offs, cnt, h, out, acc);
    } else {
        float* h2 = (float*)w8 + 256;
        hipMemsetAsync(d_out, 0, (size_t)out_size * sizeof(float), stream);
        k_linear        <<<1024, 256, 0, stream>>>(x, Wm, Wb, u, h2, acc + 32, acc + 64);
        k_scatter_atomic<<<8192, 256, 0, stream>>>(h2, w, src, dst, out);
        k_colsum        <<<2048, 256, 0, stream>>>(out, acc);
    }

    k_final<<<1, 1, 0, stream>>>(acc, out + (size_t)N_NODES * NC);
}